// Round 11
// baseline (66.623 us; speedup 1.0000x reference)
//
#include <hip/hip_runtime.h>
#include <math.h>

typedef unsigned short u16;
typedef __bf16 bf16x8 __attribute__((ext_vector_type(8)));
typedef float f32x4 __attribute__((ext_vector_type(4)));

#define B_ 32
#define W_ 512
#define H_ 768
#define HH_ 384
#define E_ 128
#define R_ 1024
#define BE_ 4096
#define K1_ 1536
#define BKK 64

__device__ __forceinline__ u16 f2bf(float f) {
  unsigned u = __float_as_uint(f);
  u = (u + 0x7fffu + ((u >> 16) & 1u)) >> 16;   // RNE
  return (u16)u;
}
__device__ __forceinline__ float bf2f(u16 u) {
  return __uint_as_float(((unsigned)u) << 16);
}
__device__ __forceinline__ void gload_lds16(const void* g, void* l) {
  __builtin_amdgcn_global_load_lds(
      (__attribute__((address_space(1))) void*)(g),
      (__attribute__((address_space(3))) void*)(l), 16, 0, 0);
}

// ---------------------------------------------------------------------------
// prep: W1c conversion, P table, entity token gather (only GEMM1's deps).
// ---------------------------------------------------------------------------
#define NBLK_W1 1152    /* 294912 float4 units / 256 */
#define NBLK_P  1152
#define NBLK_X  4096

__global__ __launch_bounds__(256) void prep_all(
    const float* __restrict__ Wh1, const float* __restrict__ Wt1,
    const float* __restrict__ bh1, const float* __restrict__ bt1,
    const float* __restrict__ emb,
    const float* __restrict__ hs, const int* __restrict__ ent_start,
    u16* __restrict__ W1c, float* __restrict__ P, u16* __restrict__ X)
{
  const int blk = blockIdx.x;
  const int tid = threadIdx.x;

  if (blk < NBLK_W1) {
    const int i = blk * 256 + tid;
    int row = i / 192, c = i % 192;
    const float4* src = (const float4*)((row < 768)
        ? (Wh1 + (size_t)row * K1_) : (Wt1 + (size_t)(row - 768) * K1_));
    float4 v = src[c];
    ushort4 o; o.x = f2bf(v.x); o.y = f2bf(v.y); o.z = f2bf(v.z); o.w = f2bf(v.w);
    ((ushort4*)W1c)[i] = o;
  } else if (blk < NBLK_W1 + NBLK_P) {
    const int w = (blk - NBLK_W1) * 4 + (tid >> 6);
    const int lane = tid & 63;
    const int l = w / K1_;
    const int n = w - l * K1_;
    const float* wrow = (n < 768) ? (Wh1 + (size_t)n * K1_ + 768)
                                  : (Wt1 + (size_t)(n - 768) * K1_ + 768);
    const float bb = (n < 768) ? bh1[n] : bt1[n - 768];
    const float* ev = emb + (size_t)l * H_;
    float s = 0.f;
#pragma unroll
    for (int t = 0; t < 12; ++t) {
      int d = lane + 64 * t;
      s += ev[d] * wrow[d];
    }
#pragma unroll
    for (int off = 32; off; off >>= 1) s += __shfl_down(s, off);
    if (lane == 0) P[(size_t)l * K1_ + n] = s + bb;
  } else {
    const int be = blk - (NBLK_W1 + NBLK_P);
    if (tid < 192) {
      int b = be >> 7;
      int start = ent_start[be];
      float4 v = ((const float4*)(hs + ((size_t)b * W_ + start) * H_))[tid];
      ushort4 o; o.x = f2bf(v.x); o.y = f2bf(v.y); o.z = f2bf(v.z); o.w = f2bf(v.w);
      ((ushort4*)(X + (size_t)be * H_))[tid] = o;
    }
  }
}

// ---------------------------------------------------------------------------
// bf16 MFMA GEMM template (counted vmcnt + raw s_barrier, R8-proven pipeline)
// TBM x TBN tile, 4 waves (2x2, each (TBM/2)x(TBN/2)). Linear LDS +
// pre-swizzled source (XOR row&7). Blocks with id >= ngemm run tail work:
//   conv tail (tW2c): W2c/Wb/b2cat bf16 conversion     (dispatch G1)
//   lin  tail (linHT): per-entity W_lin dots + out zero (dispatch G3)
// ---------------------------------------------------------------------------
template<int TBM, int TBN>
__global__ __launch_bounds__(256, 2) void gemm_bf16(
    const u16* __restrict__ A, int lda,
    const u16* __restrict__ Wt,              // [N][K] row-major
    const float* __restrict__ bias,
    u16* __restrict__ C, int ldc,
    int K, int do_relu, int half_n, int aoff,
    const float* __restrict__ rowBias,       // P [3][ldP] or null
    const int* __restrict__ rowLabel, int ldP,
    int ngemm,
    const float* __restrict__ tWh2, const float* __restrict__ tWt2,
    const float* __restrict__ tWbil,
    const float* __restrict__ tbh2, const float* __restrict__ tbt2,
    u16* __restrict__ tW2c, u16* __restrict__ tWb, float* __restrict__ tb2cat,
    const u16* __restrict__ linSrc, const float* __restrict__ W_lin,
    float* __restrict__ linHT, float* __restrict__ outZ)
{
  constexpr int FM = TBM / 32;
  constexpr int FN = TBN / 32;
  constexpr int AU = TBM / 8;              // A staging units (1KB each)
  constexpr int UNITS = (TBM + TBN) / 8;
  constexpr int UPW = UNITS / 4;
  constexpr int BUFB = (TBM + TBN) * 128;

  __shared__ char smem[2 * BUFB];

  const int tid = threadIdx.x;
  const int id  = blockIdx.y * gridDim.x + blockIdx.x;

  if (id >= ngemm) {
    const int tailid = id - ngemm;
    const int ntail  = gridDim.x * gridDim.y - ngemm;
    if (tW2c) {
      // ---- conversion tail: W2c (147456 u4) + Wb (73728) + b2cat (192) ----
      for (int i = tailid * 256 + tid; i < 221376; i += ntail * 256) {
        if (i < 147456) {
          float4 v = (i < 73728) ? ((const float4*)tWh2)[i]
                                 : ((const float4*)tWt2)[i - 73728];
          ushort4 o; o.x = f2bf(v.x); o.y = f2bf(v.y); o.z = f2bf(v.z); o.w = f2bf(v.w);
          ((ushort4*)tW2c)[i] = o;
        } else if (i < 221184) {
          int j = i - 147456;
          float4 v = ((const float4*)tWbil)[j];
          ushort4 o; o.x = f2bf(v.x); o.y = f2bf(v.y); o.z = f2bf(v.z); o.w = f2bf(v.w);
          ((ushort4*)tWb)[j] = o;
        } else {
          int j = i - 221184;
          ((float4*)tb2cat)[j] = (j < 96) ? ((const float4*)tbh2)[j]
                                          : ((const float4*)tbt2)[j - 96];
        }
      }
    } else if (linHT) {
      // ---- lin tail: linHT[be] = {h.Wl0h, h.Wl1h, t.Wl0t, t.Wl1t} ----
      if (tailid == 0 && tid == 0) outZ[0] = 0.f;
      const int wave  = tailid * 4 + (tid >> 6);
      const int nwave = ntail * 4;
      const int lane  = tid & 63;
      for (int be = wave; be < BE_; be += nwave) {
        const ushort4* src = (const ushort4*)(linSrc + (size_t)be * 768);
        float s0 = 0.f, s1 = 0.f, s2 = 0.f, s3 = 0.f;
#pragma unroll
        for (int rd = 0; rd < 3; ++rd) {
          const int idx4 = rd * 64 + lane;
          const int c = idx4 * 4;
          ushort4 v4 = src[idx4];
          float4 w0 = *(const float4*)(W_lin + c);
          float4 w1 = *(const float4*)(W_lin + 768 + c);
          float d0 = bf2f(v4.x)*w0.x + bf2f(v4.y)*w0.y + bf2f(v4.z)*w0.z + bf2f(v4.w)*w0.w;
          float d1 = bf2f(v4.x)*w1.x + bf2f(v4.y)*w1.y + bf2f(v4.z)*w1.z + bf2f(v4.w)*w1.w;
          if (c < 384) { s0 += d0; s1 += d1; }
          else         { s2 += d0; s3 += d1; }
        }
#pragma unroll
        for (int off = 32; off; off >>= 1) {
          s0 += __shfl_down(s0, off);
          s1 += __shfl_down(s1, off);
          s2 += __shfl_down(s2, off);
          s3 += __shfl_down(s3, off);
        }
        if (lane == 0) {
          float4 v = {s0, s1, s2, s3};
          *(float4*)(linHT + (size_t)be * 4) = v;
        }
      }
    }
    return;
  }

  // bijective XCD-chunked swizzle over the ngemm gemm blocks
  const int q = ngemm >> 3, r = ngemm & 7;
  const int xcd = id & 7, idx = id >> 3;
  const int wgid = (xcd < r ? xcd * (q + 1) : r * (q + 1) + (xcd - r) * q) + idx;
  const int nbx = gridDim.x;
  const int bn = (wgid % nbx) * TBN;
  const int bm = (wgid / nbx) * TBM;

  const int wid  = tid >> 6;
  const int lane = tid & 63;
  const int wm = (wid >> 1) * (TBM / 2);
  const int wn = (wid & 1) * (TBN / 2);

  const int a0 = (half_n && bn >= half_n) ? aoff : 0;

  const int srow = lane >> 3;
  const int sk8  = (lane & 7) ^ srow;
  const u16* gA = A  + (size_t)(bm + srow) * lda + a0 + 8 * sk8;
  const u16* gB = Wt + (size_t)(bn + srow) * K + 8 * sk8;

  const int frow = lane & 15;
  const int fk8  = lane >> 4;

  f32x4 acc[FM][FN] = {};

  auto stage = [&](int buf, int k0) {
    char* base = smem + buf * BUFB;
#pragma unroll
    for (int i = 0; i < UPW; ++i) {
      const int u = wid * UPW + i;
      if (u < AU)
        gload_lds16(gA + (size_t)(u * 8) * lda + k0, base + u * 1024);
      else
        gload_lds16(gB + (size_t)((u - AU) * 8) * K + k0, base + u * 1024);
    }
  };

  const int nt = K / BKK;
  stage(0, 0);                               // UPW loads in flight

  for (int t = 0; t < nt; ++t) {
    const int cur = t & 1;
    if (t + 1 < nt) {
      stage(cur ^ 1, (t + 1) * BKK);         // +UPW in flight
      asm volatile("s_waitcnt vmcnt(%0)" :: "n"(UPW) : "memory");
    } else {
      asm volatile("s_waitcnt vmcnt(0)" ::: "memory");
    }
    __builtin_amdgcn_s_barrier();            // all waves' stage(t) landed

    char* As = smem + cur * BUFB;
    char* Bs = As + TBM * 128;
#pragma unroll
    for (int kh = 0; kh < 2; ++kh) {
      bf16x8 a[FM], b[FN];
#pragma unroll
      for (int m = 0; m < FM; ++m) {
        const int row  = wm + m * 16 + frow;
        const int slot = (kh * 4 + fk8) ^ (row & 7);
        a[m] = *(const bf16x8*)(As + row * 128 + slot * 16);
      }
#pragma unroll
      for (int n = 0; n < FN; ++n) {
        const int row  = wn + n * 16 + frow;
        const int slot = (kh * 4 + fk8) ^ (row & 7);
        b[n] = *(const bf16x8*)(Bs + row * 128 + slot * 16);
      }
#pragma unroll
      for (int m = 0; m < FM; ++m)
#pragma unroll
        for (int n = 0; n < FN; ++n)
          acc[m][n] = __builtin_amdgcn_mfma_f32_16x16x32_bf16(
              a[m], b[n], acc[m][n], 0, 0, 0);
    }

    if (t + 1 < nt)
      __builtin_amdgcn_s_barrier();   // reads of cur done before overwrite
  }

  int lbl[FM][4];
  if (rowLabel) {
#pragma unroll
    for (int m = 0; m < FM; ++m)
#pragma unroll
      for (int r2 = 0; r2 < 4; ++r2)
        lbl[m][r2] = rowLabel[bm + wm + m * 16 + fk8 * 4 + r2];
  }

#pragma unroll
  for (int n = 0; n < FN; ++n) {
    const int col = bn + wn + n * 16 + frow;
    const float bv = bias ? bias[col] : 0.f;
    float p0 = 0.f, p1 = 0.f, p2 = 0.f;
    if (rowLabel) {
      p0 = rowBias[col];
      p1 = rowBias[ldP + col];
      p2 = rowBias[2 * ldP + col];
    }
#pragma unroll
    for (int m = 0; m < FM; ++m) {
#pragma unroll
      for (int r2 = 0; r2 < 4; ++r2) {
        const int row = bm + wm + m * 16 + fk8 * 4 + r2;
        float v = acc[m][n][r2] + bv;
        if (rowLabel) {
          int l = lbl[m][r2];
          v += (l == 0) ? p0 : ((l == 1) ? p1 : p2);
        }
        if (do_relu) v = fmaxf(v, 0.f);
        C[(size_t)row * ldc + col] = f2bf(v);
      }
    }
  }
}

// ---------------------------------------------------------------------------
// Fused score-GEMM + CE (R8-proven). One block per (doc-half bm, e2-quarter
// bn): 64x64 S-tile in LDS, then CE over the doc's relations in this tile.
// grid = 256, 4 waves, K=384.
// ---------------------------------------------------------------------------
__global__ __launch_bounds__(256, 2) void gemm_S_ce(
    const u16* __restrict__ Hcat, const u16* __restrict__ U,
    const float* __restrict__ linHT, const float* __restrict__ b_lin,
    const int* __restrict__ rel_head, const int* __restrict__ rel_tail,
    const int* __restrict__ rel_label, float* __restrict__ out)
{
  __shared__ char smem[2 * 16384];
  __shared__ float Sl[64][65];
  __shared__ float red[4];

  const int xcd = blockIdx.x & 7, idx = blockIdx.x >> 3;
  const int wgid = xcd * 32 + idx;
  const int bn = (wgid & 3) * 64;
  const int zz = wgid >> 2;
  const int z  = zz >> 1;
  const int bm = (zz & 1) * 64;

  const int tid  = threadIdx.x;
  const int wid  = tid >> 6;
  const int lane = tid & 63;
  const int srow = lane >> 3;
  const int sk8  = (lane & 7) ^ srow;

  auto stage = [&](int buf, int k0) {
    char* base = smem + buf * 16384;
#pragma unroll
    for (int i = 0; i < 4; ++i) {
      const int u = wid * 4 + i;
      if (u < 8) {
        const int row = z*128 + bm + u*8 + srow;
        gload_lds16(Hcat + (size_t)row * 768 + k0 + 8*sk8, base + u*1024);
      } else {
        const int row = bn + (u - 8)*8 + srow;
        gload_lds16(U + (size_t)z*98304 + (size_t)row * 384 + k0 + 8*sk8,
                    base + u*1024);
      }
    }
  };

  const int wm = (wid >> 1) * 32;
  const int wn = (wid & 1) * 32;
  const int frow = lane & 15;
  const int fk8  = lane >> 4;

  f32x4 acc[2][2] = {};

  stage(0, 0);

  for (int t = 0; t < 6; ++t) {
    const int cur = t & 1;
    if (t + 1 < 6) {
      stage(cur ^ 1, (t + 1) * BKK);
      asm volatile("s_waitcnt vmcnt(4)" ::: "memory");
    } else {
      asm volatile("s_waitcnt vmcnt(0)" ::: "memory");
    }
    __builtin_amdgcn_s_barrier();

    char* As = smem + cur * 16384;
    char* Bs = As + 8192;
#pragma unroll
    for (int kh = 0; kh < 2; ++kh) {
      bf16x8 a[2], b[2];
#pragma unroll
      for (int m = 0; m < 2; ++m) {
        const int row  = wm + m*16 + frow;
        const int slot = (kh*4 + fk8) ^ (row & 7);
        a[m] = *(const bf16x8*)(As + row*128 + slot*16);
      }
#pragma unroll
      for (int n = 0; n < 2; ++n) {
        const int row  = wn + n*16 + frow;
        const int slot = (kh*4 + fk8) ^ (row & 7);
        b[n] = *(const bf16x8*)(Bs + row*128 + slot*16);
      }
#pragma unroll
      for (int m = 0; m < 2; ++m)
#pragma unroll
        for (int n = 0; n < 2; ++n)
          acc[m][n] = __builtin_amdgcn_mfma_f32_16x16x32_bf16(
              a[m], b[n], acc[m][n], 0, 0, 0);
    }

    if (t + 1 < 6)
      __builtin_amdgcn_s_barrier();
  }

  const int o = frow & 1;
  const float blv = b_lin[o];
#pragma unroll
  for (int n = 0; n < 2; ++n) {
    const int lc = wn + n*16 + frow;
    const int e2 = (bn + lc) >> 1;
    const float lt = linHT[(size_t)(z*128 + e2) * 4 + 2 + o];
#pragma unroll
    for (int m = 0; m < 2; ++m) {
#pragma unroll
      for (int r = 0; r < 4; ++r) {
        const int lr = wm + m*16 + fk8*4 + r;
        const float lh = linHT[(size_t)(z*128 + bm + lr) * 4 + o];
        Sl[lr][lc] = acc[m][n][r] + lh + lt + blv;
      }
    }
  }
  __syncthreads();

  float nllsum = 0.f;
#pragma unroll
  for (int j = 0; j < 4; ++j) {
    const int i = z * 1024 + tid + 256 * j;
    const int rh = rel_head[i];
    const int rt = rel_tail[i];
    const int lab = rel_label[i];
    if ((unsigned)(rh - bm) < 64u && (unsigned)(rt*2 - bn) < 64u) {
      const float l0 = Sl[rh - bm][rt*2 - bn];
      const float l1 = Sl[rh - bm][rt*2 - bn + 1];
      const float mx = fmaxf(l0, l1);
      const float lse = mx + logf(expf(l0 - mx) + expf(l1 - mx));
      nllsum += lse - (lab == 0 ? l0 : l1);
    }
  }
#pragma unroll
  for (int off = 32; off; off >>= 1) nllsum += __shfl_down(nllsum, off);
  if (lane == 0) red[wid] = nllsum;
  __syncthreads();
  if (tid == 0)
    atomicAdd(out, (red[0] + red[1] + red[2] + red[3]) * (1.0f / R_));
}

// ---------------------------------------------------------------------------
extern "C" void kernel_launch(void* const* d_in, const int* in_sizes, int n_in,
                              void* d_out, int out_size, void* d_ws, size_t ws_size,
                              hipStream_t stream)
{
  const float* hs        = (const float*)d_in[0];
  const int*   rel_head  = (const int*)  d_in[1];
  const int*   rel_tail  = (const int*)  d_in[2];
  const int*   rel_label = (const int*)  d_in[3];
  const int*   ent_start = (const int*)  d_in[4];
  const int*   ent_label = (const int*)  d_in[6];
  const float* emb   = (const float*)d_in[7];
  const float* Wh1   = (const float*)d_in[8];
  const float* bh1   = (const float*)d_in[9];
  const float* Wh2   = (const float*)d_in[10];
  const float* bh2   = (const float*)d_in[11];
  const float* Wt1   = (const float*)d_in[12];
  const float* bt1   = (const float*)d_in[13];
  const float* Wt2   = (const float*)d_in[14];
  const float* bt2   = (const float*)d_in[15];
  const float* Wbil  = (const float*)d_in[16];
  const float* W_lin = (const float*)d_in[17];
  const float* b_lin = (const float*)d_in[18];
  float* out = (float*)d_out;

  // workspace layout
  u16* X    = (u16*)d_ws;                 // 4096*768
  u16* H1   = X    + (size_t)BE_ * H_;    // 4096*1536
  u16* Hcat = H1   + (size_t)BE_ * K1_;   // 4096*768
  u16* U    = Hcat + (size_t)BE_ * H_;    // 4096*768
  u16* W1c  = U    + (size_t)BE_ * H_;    // 1536*768
  u16* W2c  = W1c  + (size_t)K1_ * H_;    // 768*768
  u16* Wb   = W2c  + (size_t)H_ * H_;     // 768*384
  float* b2cat = (float*)(Wb + (size_t)H_ * HH_);  // 768
  float* P     = b2cat + H_;                       // 3*1536
  float* linHT = P + 3*K1_;                        // 4096*4

  // 1) prep: W1c + P + X (GEMM1's deps only)
  prep_all<<<dim3(NBLK_W1 + NBLK_P + NBLK_X), dim3(256), 0, stream>>>(
      Wh1, Wt1, bh1, bt1, emb, hs, ent_start, W1c, P, X);

  // 2) G1: H1 = relu(X @ W1c^T + P[label]) [4096,1536] K=768
  //    128x96 tiles: 32x16 = 512 gemm blocks (2/CU) + 32 conv-tail blocks
  gemm_bf16<128, 96><<<dim3(16, 34), dim3(256), 0, stream>>>(
      X, H_, W1c, (const float*)nullptr, H1, K1_, H_, 1, 0, 0,
      P, ent_label, K1_, 512,
      Wh2, Wt2, Wbil, bh2, bt2, W2c, Wb, b2cat,
      (const u16*)nullptr, (const float*)nullptr, (float*)nullptr, (float*)nullptr);

  // 3) G2: Hcat = relu([H1h@Wh2^T ; H1t@Wt2^T] + b2cat) [4096,768] K=768
  //    128x96 tiles: 32x8 = 256 blocks (1/CU, no idle CUs)
  gemm_bf16<128, 96><<<dim3(8, 32), dim3(256), 0, stream>>>(
      H1, K1_, W2c, b2cat, Hcat, H_, H_, 1, HH_, H_,
      (const float*)nullptr, (const int*)nullptr, 0, 256,
      (const float*)nullptr, (const float*)nullptr, (const float*)nullptr,
      (const float*)nullptr, (const float*)nullptr,
      (u16*)nullptr, (u16*)nullptr, (float*)nullptr,
      (const u16*)nullptr, (const float*)nullptr, (float*)nullptr, (float*)nullptr);

  // 4) G3: U = Ht @ Wbil^T [4096,768] K=384
  //    256 gemm blocks + 136 lin-tail blocks (+ out zero)
  gemm_bf16<128, 96><<<dim3(8, 49), dim3(256), 0, stream>>>(
      Hcat + HH_, H_, Wb, (const float*)nullptr, U, H_, HH_, 0, 0, 0,
      (const float*)nullptr, (const int*)nullptr, 0, 256,
      (const float*)nullptr, (const float*)nullptr, (const float*)nullptr,
      (const float*)nullptr, (const float*)nullptr,
      (u16*)nullptr, (u16*)nullptr, (float*)nullptr,
      Hcat, W_lin, linHT, out);

  // 5) fused score GEMM + CE
  gemm_S_ce<<<dim3(256), dim3(256), 0, stream>>>(
      Hcat, U, linHT, b_lin, rel_head, rel_tail, rel_label, out);
}

// Round 12
// 61.008 us; speedup vs baseline: 1.0920x; 1.0920x over previous
//
#include <hip/hip_runtime.h>
#include <math.h>

typedef unsigned short u16;
typedef __bf16 bf16x8 __attribute__((ext_vector_type(8)));
typedef float f32x4 __attribute__((ext_vector_type(4)));

#define B_ 32
#define W_ 512
#define H_ 768
#define HH_ 384
#define E_ 128
#define R_ 1024
#define BE_ 4096
#define K1_ 1536
#define BKK 64

__device__ __forceinline__ u16 f2bf(float f) {
  unsigned u = __float_as_uint(f);
  u = (u + 0x7fffu + ((u >> 16) & 1u)) >> 16;   // RNE
  return (u16)u;
}
__device__ __forceinline__ float bf2f(u16 u) {
  return __uint_as_float(((unsigned)u) << 16);
}
__device__ __forceinline__ void gload_lds16(const void* g, void* l) {
  __builtin_amdgcn_global_load_lds(
      (__attribute__((address_space(1))) void*)(g),
      (__attribute__((address_space(3))) void*)(l), 16, 0, 0);
}

// ---------------------------------------------------------------------------
// prep: W1c conversion, P table, entity token gather (only GEMM1's deps).
// ---------------------------------------------------------------------------
#define NBLK_W1 1152    /* 294912 float4 units / 256 */
#define NBLK_P  1152
#define NBLK_X  4096

__global__ __launch_bounds__(256) void prep_all(
    const float* __restrict__ Wh1, const float* __restrict__ Wt1,
    const float* __restrict__ bh1, const float* __restrict__ bt1,
    const float* __restrict__ emb,
    const float* __restrict__ hs, const int* __restrict__ ent_start,
    u16* __restrict__ W1c, float* __restrict__ P, u16* __restrict__ X)
{
  const int blk = blockIdx.x;
  const int tid = threadIdx.x;

  if (blk < NBLK_W1) {
    const int i = blk * 256 + tid;
    int row = i / 192, c = i % 192;
    const float4* src = (const float4*)((row < 768)
        ? (Wh1 + (size_t)row * K1_) : (Wt1 + (size_t)(row - 768) * K1_));
    float4 v = src[c];
    ushort4 o; o.x = f2bf(v.x); o.y = f2bf(v.y); o.z = f2bf(v.z); o.w = f2bf(v.w);
    ((ushort4*)W1c)[i] = o;
  } else if (blk < NBLK_W1 + NBLK_P) {
    const int w = (blk - NBLK_W1) * 4 + (tid >> 6);
    const int lane = tid & 63;
    const int l = w / K1_;
    const int n = w - l * K1_;
    const float* wrow = (n < 768) ? (Wh1 + (size_t)n * K1_ + 768)
                                  : (Wt1 + (size_t)(n - 768) * K1_ + 768);
    const float bb = (n < 768) ? bh1[n] : bt1[n - 768];
    const float* ev = emb + (size_t)l * H_;
    float s = 0.f;
#pragma unroll
    for (int t = 0; t < 12; ++t) {
      int d = lane + 64 * t;
      s += ev[d] * wrow[d];
    }
#pragma unroll
    for (int off = 32; off; off >>= 1) s += __shfl_down(s, off);
    if (lane == 0) P[(size_t)l * K1_ + n] = s + bb;
  } else {
    const int be = blk - (NBLK_W1 + NBLK_P);
    if (tid < 192) {
      int b = be >> 7;
      int start = ent_start[be];
      float4 v = ((const float4*)(hs + ((size_t)b * W_ + start) * H_))[tid];
      ushort4 o; o.x = f2bf(v.x); o.y = f2bf(v.y); o.z = f2bf(v.z); o.w = f2bf(v.w);
      ((ushort4*)(X + (size_t)be * H_))[tid] = o;
    }
  }
}

// ---------------------------------------------------------------------------
// bf16 MFMA GEMM template (counted vmcnt + raw s_barrier, R8/R10-proven).
// TBM x TBN tile, 4 waves (2x2, each (TBM/2)x(TBN/2)). Linear LDS +
// pre-swizzled source (XOR row&7). Blocks with id >= ngemm run tail work:
//   conv tail (tW2c): W2c/Wb/b2cat bf16 conversion      (dispatch G1)
//   lin  tail (linHT): per-entity W_lin dots + out zero (dispatch G3)
// ---------------------------------------------------------------------------
template<int TBM, int TBN>
__global__ __launch_bounds__(256, 2) void gemm_bf16(
    const u16* __restrict__ A, int lda,
    const u16* __restrict__ Wt,              // [N][K] row-major
    const float* __restrict__ bias,
    u16* __restrict__ C, int ldc,
    int K, int do_relu, int half_n, int aoff,
    const float* __restrict__ rowBias,       // P [3][ldP] or null
    const int* __restrict__ rowLabel, int ldP,
    int ngemm,
    const float* __restrict__ tWh2, const float* __restrict__ tWt2,
    const float* __restrict__ tWbil,
    const float* __restrict__ tbh2, const float* __restrict__ tbt2,
    u16* __restrict__ tW2c, u16* __restrict__ tWb, float* __restrict__ tb2cat,
    const u16* __restrict__ linSrc, const float* __restrict__ W_lin,
    float* __restrict__ linHT, float* __restrict__ outZ)
{
  constexpr int FM = TBM / 32;
  constexpr int FN = TBN / 32;
  constexpr int AU = TBM / 8;              // A staging units (1KB each)
  constexpr int UNITS = (TBM + TBN) / 8;
  constexpr int UPW = UNITS / 4;
  constexpr int BUFB = (TBM + TBN) * 128;

  __shared__ char smem[2 * BUFB];

  const int tid = threadIdx.x;
  const int id  = blockIdx.y * gridDim.x + blockIdx.x;

  if (id >= ngemm) {
    const int tailid = id - ngemm;
    const int ntail  = gridDim.x * gridDim.y - ngemm;
    if (tW2c) {
      // ---- conversion tail: W2c (147456 u4) + Wb (73728) + b2cat (192) ----
      for (int i = tailid * 256 + tid; i < 221376; i += ntail * 256) {
        if (i < 147456) {
          float4 v = (i < 73728) ? ((const float4*)tWh2)[i]
                                 : ((const float4*)tWt2)[i - 73728];
          ushort4 o; o.x = f2bf(v.x); o.y = f2bf(v.y); o.z = f2bf(v.z); o.w = f2bf(v.w);
          ((ushort4*)tW2c)[i] = o;
        } else if (i < 221184) {
          int j = i - 147456;
          float4 v = ((const float4*)tWbil)[j];
          ushort4 o; o.x = f2bf(v.x); o.y = f2bf(v.y); o.z = f2bf(v.z); o.w = f2bf(v.w);
          ((ushort4*)tWb)[j] = o;
        } else {
          int j = i - 221184;
          ((float4*)tb2cat)[j] = (j < 96) ? ((const float4*)tbh2)[j]
                                          : ((const float4*)tbt2)[j - 96];
        }
      }
    } else if (linHT) {
      // ---- lin tail: linHT[be] = {h.Wl0h, h.Wl1h, t.Wl0t, t.Wl1t} ----
      if (tailid == 0 && tid == 0) outZ[0] = 0.f;
      const int wave  = tailid * 4 + (tid >> 6);
      const int nwave = ntail * 4;
      const int lane  = tid & 63;
      for (int be = wave; be < BE_; be += nwave) {
        const ushort4* src = (const ushort4*)(linSrc + (size_t)be * 768);
        float s0 = 0.f, s1 = 0.f, s2 = 0.f, s3 = 0.f;
#pragma unroll
        for (int rd = 0; rd < 3; ++rd) {
          const int idx4 = rd * 64 + lane;
          const int c = idx4 * 4;
          ushort4 v4 = src[idx4];
          float4 w0 = *(const float4*)(W_lin + c);
          float4 w1 = *(const float4*)(W_lin + 768 + c);
          float d0 = bf2f(v4.x)*w0.x + bf2f(v4.y)*w0.y + bf2f(v4.z)*w0.z + bf2f(v4.w)*w0.w;
          float d1 = bf2f(v4.x)*w1.x + bf2f(v4.y)*w1.y + bf2f(v4.z)*w1.z + bf2f(v4.w)*w1.w;
          if (c < 384) { s0 += d0; s1 += d1; }
          else         { s2 += d0; s3 += d1; }
        }
#pragma unroll
        for (int off = 32; off; off >>= 1) {
          s0 += __shfl_down(s0, off);
          s1 += __shfl_down(s1, off);
          s2 += __shfl_down(s2, off);
          s3 += __shfl_down(s3, off);
        }
        if (lane == 0) {
          float4 v = {s0, s1, s2, s3};
          *(float4*)(linHT + (size_t)be * 4) = v;
        }
      }
    }
    return;
  }

  // bijective XCD-chunked swizzle over the ngemm gemm blocks
  const int q = ngemm >> 3, r = ngemm & 7;
  const int xcd = id & 7, idx = id >> 3;
  const int wgid = (xcd < r ? xcd * (q + 1) : r * (q + 1) + (xcd - r) * q) + idx;
  const int nbx = gridDim.x;
  const int bn = (wgid % nbx) * TBN;
  const int bm = (wgid / nbx) * TBM;

  const int wid  = tid >> 6;
  const int lane = tid & 63;
  const int wm = (wid >> 1) * (TBM / 2);
  const int wn = (wid & 1) * (TBN / 2);

  const int a0 = (half_n && bn >= half_n) ? aoff : 0;

  const int srow = lane >> 3;
  const int sk8  = (lane & 7) ^ srow;
  const u16* gA = A  + (size_t)(bm + srow) * lda + a0 + 8 * sk8;
  const u16* gB = Wt + (size_t)(bn + srow) * K + 8 * sk8;

  const int frow = lane & 15;
  const int fk8  = lane >> 4;

  f32x4 acc[FM][FN] = {};

  auto stage = [&](int buf, int k0) {
    char* base = smem + buf * BUFB;
#pragma unroll
    for (int i = 0; i < UPW; ++i) {
      const int u = wid * UPW + i;
      if (u < AU)
        gload_lds16(gA + (size_t)(u * 8) * lda + k0, base + u * 1024);
      else
        gload_lds16(gB + (size_t)((u - AU) * 8) * K + k0, base + u * 1024);
    }
  };

  const int nt = K / BKK;
  stage(0, 0);                               // UPW loads in flight

  for (int t = 0; t < nt; ++t) {
    const int cur = t & 1;
    if (t + 1 < nt) {
      stage(cur ^ 1, (t + 1) * BKK);         // +UPW in flight
      asm volatile("s_waitcnt vmcnt(%0)" :: "n"(UPW) : "memory");
    } else {
      asm volatile("s_waitcnt vmcnt(0)" ::: "memory");
    }
    __builtin_amdgcn_s_barrier();            // all waves' stage(t) landed

    char* As = smem + cur * BUFB;
    char* Bs = As + TBM * 128;
#pragma unroll
    for (int kh = 0; kh < 2; ++kh) {
      bf16x8 a[FM], b[FN];
#pragma unroll
      for (int m = 0; m < FM; ++m) {
        const int row  = wm + m * 16 + frow;
        const int slot = (kh * 4 + fk8) ^ (row & 7);
        a[m] = *(const bf16x8*)(As + row * 128 + slot * 16);
      }
#pragma unroll
      for (int n = 0; n < FN; ++n) {
        const int row  = wn + n * 16 + frow;
        const int slot = (kh * 4 + fk8) ^ (row & 7);
        b[n] = *(const bf16x8*)(Bs + row * 128 + slot * 16);
      }
#pragma unroll
      for (int m = 0; m < FM; ++m)
#pragma unroll
        for (int n = 0; n < FN; ++n)
          acc[m][n] = __builtin_amdgcn_mfma_f32_16x16x32_bf16(
              a[m], b[n], acc[m][n], 0, 0, 0);
    }

    if (t + 1 < nt)
      __builtin_amdgcn_s_barrier();   // reads of cur done before overwrite
  }

  int lbl[FM][4];
  if (rowLabel) {
#pragma unroll
    for (int m = 0; m < FM; ++m)
#pragma unroll
      for (int r2 = 0; r2 < 4; ++r2)
        lbl[m][r2] = rowLabel[bm + wm + m * 16 + fk8 * 4 + r2];
  }

#pragma unroll
  for (int n = 0; n < FN; ++n) {
    const int col = bn + wn + n * 16 + frow;
    const float bv = bias ? bias[col] : 0.f;
    float p0 = 0.f, p1 = 0.f, p2 = 0.f;
    if (rowLabel) {
      p0 = rowBias[col];
      p1 = rowBias[ldP + col];
      p2 = rowBias[2 * ldP + col];
    }
#pragma unroll
    for (int m = 0; m < FM; ++m) {
#pragma unroll
      for (int r2 = 0; r2 < 4; ++r2) {
        const int row = bm + wm + m * 16 + fk8 * 4 + r2;
        float v = acc[m][n][r2] + bv;
        if (rowLabel) {
          int l = lbl[m][r2];
          v += (l == 0) ? p0 : ((l == 1) ? p1 : p2);
        }
        if (do_relu) v = fmaxf(v, 0.f);
        C[(size_t)row * ldc + col] = f2bf(v);
      }
    }
  }
}

// ---------------------------------------------------------------------------
// Fused score-GEMM + CE (R8-proven). One block per (doc-half bm, e2-quarter
// bn): 64x64 S-tile in LDS, then CE over the doc's relations in this tile.
// grid = 256, 4 waves, K=384.
// ---------------------------------------------------------------------------
__global__ __launch_bounds__(256, 2) void gemm_S_ce(
    const u16* __restrict__ Hcat, const u16* __restrict__ U,
    const float* __restrict__ linHT, const float* __restrict__ b_lin,
    const int* __restrict__ rel_head, const int* __restrict__ rel_tail,
    const int* __restrict__ rel_label, float* __restrict__ out)
{
  __shared__ char smem[2 * 16384];
  __shared__ float Sl[64][65];
  __shared__ float red[4];

  const int xcd = blockIdx.x & 7, idx = blockIdx.x >> 3;
  const int wgid = xcd * 32 + idx;
  const int bn = (wgid & 3) * 64;
  const int zz = wgid >> 2;
  const int z  = zz >> 1;
  const int bm = (zz & 1) * 64;

  const int tid  = threadIdx.x;
  const int wid  = tid >> 6;
  const int lane = tid & 63;
  const int srow = lane >> 3;
  const int sk8  = (lane & 7) ^ srow;

  auto stage = [&](int buf, int k0) {
    char* base = smem + buf * 16384;
#pragma unroll
    for (int i = 0; i < 4; ++i) {
      const int u = wid * 4 + i;
      if (u < 8) {
        const int row = z*128 + bm + u*8 + srow;
        gload_lds16(Hcat + (size_t)row * 768 + k0 + 8*sk8, base + u*1024);
      } else {
        const int row = bn + (u - 8)*8 + srow;
        gload_lds16(U + (size_t)z*98304 + (size_t)row * 384 + k0 + 8*sk8,
                    base + u*1024);
      }
    }
  };

  const int wm = (wid >> 1) * 32;
  const int wn = (wid & 1) * 32;
  const int frow = lane & 15;
  const int fk8  = lane >> 4;

  f32x4 acc[2][2] = {};

  stage(0, 0);

  for (int t = 0; t < 6; ++t) {
    const int cur = t & 1;
    if (t + 1 < 6) {
      stage(cur ^ 1, (t + 1) * BKK);
      asm volatile("s_waitcnt vmcnt(4)" ::: "memory");
    } else {
      asm volatile("s_waitcnt vmcnt(0)" ::: "memory");
    }
    __builtin_amdgcn_s_barrier();

    char* As = smem + cur * 16384;
    char* Bs = As + 8192;
#pragma unroll
    for (int kh = 0; kh < 2; ++kh) {
      bf16x8 a[2], b[2];
#pragma unroll
      for (int m = 0; m < 2; ++m) {
        const int row  = wm + m*16 + frow;
        const int slot = (kh*4 + fk8) ^ (row & 7);
        a[m] = *(const bf16x8*)(As + row*128 + slot*16);
      }
#pragma unroll
      for (int n = 0; n < 2; ++n) {
        const int row  = wn + n*16 + frow;
        const int slot = (kh*4 + fk8) ^ (row & 7);
        b[n] = *(const bf16x8*)(Bs + row*128 + slot*16);
      }
#pragma unroll
      for (int m = 0; m < 2; ++m)
#pragma unroll
        for (int n = 0; n < 2; ++n)
          acc[m][n] = __builtin_amdgcn_mfma_f32_16x16x32_bf16(
              a[m], b[n], acc[m][n], 0, 0, 0);
    }

    if (t + 1 < 6)
      __builtin_amdgcn_s_barrier();
  }

  const int o = frow & 1;
  const float blv = b_lin[o];
#pragma unroll
  for (int n = 0; n < 2; ++n) {
    const int lc = wn + n*16 + frow;
    const int e2 = (bn + lc) >> 1;
    const float lt = linHT[(size_t)(z*128 + e2) * 4 + 2 + o];
#pragma unroll
    for (int m = 0; m < 2; ++m) {
#pragma unroll
      for (int r = 0; r < 4; ++r) {
        const int lr = wm + m*16 + fk8*4 + r;
        const float lh = linHT[(size_t)(z*128 + bm + lr) * 4 + o];
        Sl[lr][lc] = acc[m][n][r] + lh + lt + blv;
      }
    }
  }
  __syncthreads();

  float nllsum = 0.f;
#pragma unroll
  for (int j = 0; j < 4; ++j) {
    const int i = z * 1024 + tid + 256 * j;
    const int rh = rel_head[i];
    const int rt = rel_tail[i];
    const int lab = rel_label[i];
    if ((unsigned)(rh - bm) < 64u && (unsigned)(rt*2 - bn) < 64u) {
      const float l0 = Sl[rh - bm][rt*2 - bn];
      const float l1 = Sl[rh - bm][rt*2 - bn + 1];
      const float mx = fmaxf(l0, l1);
      const float lse = mx + logf(expf(l0 - mx) + expf(l1 - mx));
      nllsum += lse - (lab == 0 ? l0 : l1);
    }
  }
#pragma unroll
  for (int off = 32; off; off >>= 1) nllsum += __shfl_down(nllsum, off);
  if (lane == 0) red[wid] = nllsum;
  __syncthreads();
  if (tid == 0)
    atomicAdd(out, (red[0] + red[1] + red[2] + red[3]) * (1.0f / R_));
}

// ---------------------------------------------------------------------------
extern "C" void kernel_launch(void* const* d_in, const int* in_sizes, int n_in,
                              void* d_out, int out_size, void* d_ws, size_t ws_size,
                              hipStream_t stream)
{
  const float* hs        = (const float*)d_in[0];
  const int*   rel_head  = (const int*)  d_in[1];
  const int*   rel_tail  = (const int*)  d_in[2];
  const int*   rel_label = (const int*)  d_in[3];
  const int*   ent_start = (const int*)  d_in[4];
  const int*   ent_label = (const int*)  d_in[6];
  const float* emb   = (const float*)d_in[7];
  const float* Wh1   = (const float*)d_in[8];
  const float* bh1   = (const float*)d_in[9];
  const float* Wh2   = (const float*)d_in[10];
  const float* bh2   = (const float*)d_in[11];
  const float* Wt1   = (const float*)d_in[12];
  const float* bt1   = (const float*)d_in[13];
  const float* Wt2   = (const float*)d_in[14];
  const float* bt2   = (const float*)d_in[15];
  const float* Wbil  = (const float*)d_in[16];
  const float* W_lin = (const float*)d_in[17];
  const float* b_lin = (const float*)d_in[18];
  float* out = (float*)d_out;

  // workspace layout
  u16* X    = (u16*)d_ws;                 // 4096*768
  u16* H1   = X    + (size_t)BE_ * H_;    // 4096*1536
  u16* Hcat = H1   + (size_t)BE_ * K1_;   // 4096*768
  u16* U    = Hcat + (size_t)BE_ * H_;    // 4096*768
  u16* W1c  = U    + (size_t)BE_ * H_;    // 1536*768
  u16* W2c  = W1c  + (size_t)K1_ * H_;    // 768*768
  u16* Wb   = W2c  + (size_t)H_ * H_;     // 768*384
  float* b2cat = (float*)(Wb + (size_t)H_ * HH_);  // 768
  float* P     = b2cat + H_;                       // 3*1536
  float* linHT = P + 3*K1_;                        // 4096*4

  // 1) prep: W1c + P + X (GEMM1's deps only)
  prep_all<<<dim3(NBLK_W1 + NBLK_P + NBLK_X), dim3(256), 0, stream>>>(
      Wh1, Wt1, bh1, bt1, emb, hs, ent_start, W1c, P, X);

  // 2) G1: H1 = relu(X @ W1c^T + P[label]) [4096,1536] K=768
  //    128x128 tiles (R10-proven): 384 gemm blocks + 24 conv-tail blocks
  gemm_bf16<128, 128><<<dim3(12, 34), dim3(256), 0, stream>>>(
      X, H_, W1c, (const float*)nullptr, H1, K1_, H_, 1, 0, 0,
      P, ent_label, K1_, 384,
      Wh2, Wt2, Wbil, bh2, bt2, W2c, Wb, b2cat,
      (const u16*)nullptr, (const float*)nullptr, (float*)nullptr, (float*)nullptr);

  // 3) G2: Hcat = relu([H1h@Wh2^T ; H1t@Wt2^T] + b2cat) [4096,768] K=768
  //    128x96 tiles: 8x32 = 256 blocks (exactly 1/CU, no idle CUs)
  gemm_bf16<128, 96><<<dim3(8, 32), dim3(256), 0, stream>>>(
      H1, K1_, W2c, b2cat, Hcat, H_, H_, 1, HH_, H_,
      (const float*)nullptr, (const int*)nullptr, 0, 256,
      (const float*)nullptr, (const float*)nullptr, (const float*)nullptr,
      (const float*)nullptr, (const float*)nullptr,
      (u16*)nullptr, (u16*)nullptr, (float*)nullptr,
      (const u16*)nullptr, (const float*)nullptr, (float*)nullptr, (float*)nullptr);

  // 4) G3: U = Ht @ Wbil^T [4096,768] K=384
  //    128x96: 256 gemm blocks + 136 lin-tail blocks (+ out zero)
  gemm_bf16<128, 96><<<dim3(8, 49), dim3(256), 0, stream>>>(
      Hcat + HH_, H_, Wb, (const float*)nullptr, U, H_, HH_, 0, 0, 0,
      (const float*)nullptr, (const int*)nullptr, 0, 256,
      (const float*)nullptr, (const float*)nullptr, (const float*)nullptr,
      (const float*)nullptr, (const float*)nullptr,
      (u16*)nullptr, (u16*)nullptr, (float*)nullptr,
      Hcat, W_lin, linHT, out);

  // 5) fused score GEMM + CE
  gemm_S_ce<<<dim3(256), dim3(256), 0, stream>>>(
      Hcat, U, linHT, b_lin, rel_head, rel_tail, rel_label, out);
}